// Round 2
// baseline (429.208 us; speedup 1.0000x reference)
//
#include <hip/hip_runtime.h>

typedef unsigned short u16;
typedef _Float16 f16x8 __attribute__((ext_vector_type(8)));
typedef float f32x4 __attribute__((ext_vector_type(4)));

__device__ __forceinline__ u16 f2h(float f){
  _Float16 h = (_Float16)f; u16 u; __builtin_memcpy(&u, &h, 2); return u;
}
__device__ __forceinline__ float h2f(u16 u){
  _Float16 h; __builtin_memcpy(&h, &u, 2); return (float)h;
}
__device__ __forceinline__ float sigm(float x){ return 1.0f/(1.0f + __expf(-x)); }
__device__ __forceinline__ f32x4 zero4(){ f32x4 z; z[0]=0.f; z[1]=0.f; z[2]=0.f; z[3]=0.f; return z; }

// element-level XOR swizzle for 256B (128 x f16) rows: flips elem bits 3..5 by row&7
#define SWZ8(row,k) ((k) ^ (((row)&7)<<3))

// ---------------- prep: pack weights to f16 ----------------
// W1[512][128]: row 2n = p_in_w[n,:], row 2n+1 = g_in_w[n,:]
// Wgo[128][128] = g_out_w ; Wpo[128][128] = p_out_w
__global__ void k_prep(const float* __restrict__ p_in, const float* __restrict__ g_in,
                       const float* __restrict__ g_out, const float* __restrict__ p_out,
                       u16* __restrict__ W1, u16* __restrict__ Wgo, u16* __restrict__ Wpo){
  int t = blockIdx.x*256 + threadIdx.x;
  if (t < 65536){
    int row = t >> 7, k = t & 127, n = row >> 1;
    W1[t] = f2h((row & 1) ? g_in[n*128+k] : p_in[n*128+k]);
  } else if (t < 81920){
    int u = t - 65536; Wgo[u] = f2h(g_out[u]);
  } else if (t < 98304){
    int u = t - 81920; Wpo[u] = f2h(p_out[u]);
  }
}

// ---------------- S1: LN + in-projections + gate, transposed a/b store ----------------
// rows r = i*512+k (262144 total), block handles 128 rows. a_t/b_t: [128 d][262144 r] f16.
// gate: [262144 r][128 d] f16.
__global__ __launch_bounds__(256) void k_s1(
    const float* __restrict__ x, const float* __restrict__ mask,
    const float* __restrict__ nw, const float* __restrict__ nb,
    const u16* __restrict__ W1, const u16* __restrict__ Wgo,
    u16* __restrict__ a_t, u16* __restrict__ b_t, u16* __restrict__ gate)
{
  __shared__ u16 x_s[128*128];   // x_in f16, swizzled rows
  __shared__ u16 w_s[64*128];    // weight chunk, swizzled rows
  __shared__ u16 h_s[128*68];    // staging (a/b: [32][128]; gate: [128][68])
  __shared__ float mask_s[128];

  const int tid = threadIdx.x, lane = tid & 63, w = tid >> 6;
  const int col = lane & 15, hi = lane >> 4;
  const int r0 = blockIdx.x * 128;

  if (tid < 128) mask_s[tid] = mask[r0 + tid];
  float2 nwv = *(const float2*)(nw + lane*2);
  float2 nbv = *(const float2*)(nb + lane*2);

  // phase 1: LayerNorm, one row per wave-iteration (float2/lane, shfl reduce)
  for (int rr = 0; rr < 32; ++rr){
    int row = w*32 + rr;
    float2 xv = *(const float2*)(x + (size_t)(r0+row)*128 + lane*2);
    float s = xv.x + xv.y, q = xv.x*xv.x + xv.y*xv.y;
    #pragma unroll
    for (int off = 32; off; off >>= 1){ s += __shfl_xor(s, off); q += __shfl_xor(q, off); }
    float mu = s * 0.0078125f;
    float rs = rsqrtf(q*0.0078125f - mu*mu + 1e-5f);
    float h0 = (xv.x - mu)*rs*nwv.x + nbv.x;
    float h1 = (xv.y - mu)*rs*nwv.y + nbv.y;
    unsigned pk = (unsigned)f2h(h0) | ((unsigned)f2h(h1) << 16);
    *(unsigned*)(&x_s[row*128 + SWZ8(row, lane*2)]) = pk;
  }

  // phase 2: 10 chunks of 64 output cols (8 paired p/g chunks, 2 gate chunks)
  for (int c = 0; c < 10; ++c){
    const u16* wsrc = (c < 8) ? (W1 + c*64*128) : (Wgo + (c-8)*64*128);
    #pragma unroll
    for (int it = 0; it < 4; ++it){
      int idx = it*256 + tid;
      int n = idx >> 4, kb = (idx & 15) * 8;
      uint4 v = *(const uint4*)(wsrc + n*128 + kb);
      *(uint4*)(&w_s[n*128 + SWZ8(n, kb)]) = v;
    }
    __syncthreads();

    f32x4 acc[2][4];
    #pragma unroll
    for (int m=0;m<2;m++){
      #pragma unroll
      for (int n=0;n<4;n++) acc[m][n] = zero4();
    }

    #pragma unroll
    for (int kk = 0; kk < 4; ++kk){
      f16x8 af[2], bv[4];
      #pragma unroll
      for (int m=0;m<2;m++){
        int row = w*32 + m*16 + col;
        af[m] = *(const f16x8*)(&x_s[row*128 + SWZ8(row, kk*32 + hi*8)]);
      }
      #pragma unroll
      for (int n=0;n<4;n++){
        int rw = n*16 + col;
        bv[n] = *(const f16x8*)(&w_s[rw*128 + SWZ8(rw, kk*32 + hi*8)]);
      }
      #pragma unroll
      for (int m=0;m<2;m++){
        #pragma unroll
        for (int n=0;n<4;n++)
          acc[m][n] = __builtin_amdgcn_mfma_f32_16x16x32_f16(af[m], bv[n], acc[m][n], 0, 0, 0);
      }
    }

    if (c < 8){
      // paired cols: even = p, odd = g.  h = p * sigmoid(g) * mask
      const bool is_p = ((col & 1) == 0);
      #pragma unroll
      for (int m=0;m<2;m++){
        #pragma unroll
        for (int n=0;n<4;n++){
          float ov[4];
          #pragma unroll
          for (int j=0;j<4;j++) ov[j] = __shfl_xor(acc[m][n][j], 1);
          if (is_p){
            int dl = n*8 + (col >> 1);
            int rb = w*32 + m*16 + hi*4;
            unsigned long long pk = 0ull;
            #pragma unroll
            for (int j=0;j<4;j++){
              float h = acc[m][n][j] * sigm(ov[j]) * mask_s[rb + j];
              pk |= ((unsigned long long)f2h(h)) << (16*j);
            }
            *(unsigned long long*)(&h_s[dl*128 + rb]) = pk;
          }
        }
      }
      __syncthreads();
      {
        int dl = tid >> 3, seg = (tid & 7) * 16;
        int dg = c*32 + dl;
        u16* dst = (dg < 128) ? (a_t + (size_t)dg*262144 + r0)
                              : (b_t + (size_t)(dg-128)*262144 + r0);
        *(uint4*)(dst + seg)     = *(const uint4*)(&h_s[dl*128 + seg]);
        *(uint4*)(dst + seg + 8) = *(const uint4*)(&h_s[dl*128 + seg + 8]);
      }
      __syncthreads();
    } else {
      // gate chunk: gate = sigmoid(acc), row-major store
      #pragma unroll
      for (int m=0;m<2;m++){
        #pragma unroll
        for (int n=0;n<4;n++){
          #pragma unroll
          for (int j=0;j<4;j++){
            int row = w*32 + m*16 + hi*4 + j;
            h_s[row*68 + n*16 + col] = f2h(sigm(acc[m][n][j]));
          }
        }
      }
      __syncthreads();
      {
        int row = tid >> 1, base = (tid & 1) * 32;
        u16* dst = gate + (size_t)(r0+row)*128 + (c-8)*64 + base;
        #pragma unroll
        for (int i2=0;i2<4;i2++)
          *(uint4*)(dst + i2*8) = *(const uint4*)(&h_s[row*68 + base + i2*8]);
      }
      __syncthreads();
    }
  }
}

// ---------------- S2: 128 batched NT-GEMMs  t[d][i][j] = sum_k a[d][i][k] b[d][j][k] ----------------
__global__ __launch_bounds__(256) void k_s2(
    const u16* __restrict__ a_t, const u16* __restrict__ b_t, u16* __restrict__ t_dm)
{
  __shared__ u16 A_s[128*32];
  __shared__ u16 B_s[128*32];
  __shared__ u16 C_s[128*136];

  const int tid = threadIdx.x, lane = tid & 63, w = tid >> 6;
  const int col = lane & 15, hi = lane >> 4;
  const int d = blockIdx.y;
  const int ti = (blockIdx.x >> 2) * 128, tj = (blockIdx.x & 3) * 128;
  const u16* Ab = a_t + (size_t)d * 262144;
  const u16* Bb = b_t + (size_t)d * 262144;
  const int wr = (w >> 1) * 64, wc = (w & 1) * 64;

  f32x4 acc[4][4];
  #pragma unroll
  for (int m=0;m<4;m++){
    #pragma unroll
    for (int n=0;n<4;n++) acc[m][n] = zero4();
  }

  const int srow = lane >> 2;          // 0..15 row within 16-row chunk
  const int scol = (lane & 3) * 8;     // element base within 32-k tile

  for (int k0 = 0; k0 < 512; k0 += 32){
    __syncthreads();
    #pragma unroll
    for (int j = 0; j < 2; ++j){
      int chunk = w*2 + j;
      int row = chunk*16 + srow;
      int e = scol ^ ((((row >> 1) & 3)) << 3);   // source pre-swizzle (m173)
      const unsigned int* gpA = (const unsigned int*)(Ab + (size_t)(ti + row)*512 + k0 + e);
      unsigned int* lpA = (unsigned int*)(&A_s[chunk*512]);
      __builtin_amdgcn_global_load_lds((const __attribute__((address_space(1))) unsigned int*)gpA,
                                       (__attribute__((address_space(3))) unsigned int*)lpA, 16, 0, 0);
      const unsigned int* gpB = (const unsigned int*)(Bb + (size_t)(tj + row)*512 + k0 + e);
      unsigned int* lpB = (unsigned int*)(&B_s[chunk*512]);
      __builtin_amdgcn_global_load_lds((const __attribute__((address_space(1))) unsigned int*)gpB,
                                       (__attribute__((address_space(3))) unsigned int*)lpB, 16, 0, 0);
    }
    __syncthreads();

    f16x8 af[4], bfv[4];
    #pragma unroll
    for (int m=0;m<4;m++){
      int row = wr + m*16 + col;
      af[m] = *(const f16x8*)(&A_s[row*32 + (hi*8 ^ ((((row>>1)&3))<<3))]);
    }
    #pragma unroll
    for (int n=0;n<4;n++){
      int row = wc + n*16 + col;
      bfv[n] = *(const f16x8*)(&B_s[row*32 + (hi*8 ^ ((((row>>1)&3))<<3))]);
    }
    #pragma unroll
    for (int m=0;m<4;m++){
      #pragma unroll
      for (int n=0;n<4;n++)
        acc[m][n] = __builtin_amdgcn_mfma_f32_16x16x32_f16(af[m], bfv[n], acc[m][n], 0, 0, 0);
    }
  }

  // epilogue: stage f16 C tile in LDS, coalesced global write
  #pragma unroll
  for (int m=0;m<4;m++){
    #pragma unroll
    for (int n=0;n<4;n++){
      #pragma unroll
      for (int j=0;j<4;j++){
        int row = wr + m*16 + hi*4 + j, cl = wc + n*16 + col;
        C_s[row*136 + cl] = f2h(acc[m][n][j]);
      }
    }
  }
  __syncthreads();
  u16* dst0 = t_dm + (size_t)d*262144 + (size_t)ti*512 + tj;
  #pragma unroll
  for (int s=0;s<8;s++){
    int gi = s*256 + tid;
    int row = gi >> 4, seg = (gi & 15) * 8;
    *(uint4*)(dst0 + (size_t)row*512 + seg) = *(const uint4*)(&C_s[row*136 + seg]);
  }
}

// ---------------- S3: LN(t) @ p_out^T * gate -> out (f32) ----------------
__global__ __launch_bounds__(256) void k_s3(
    const u16* __restrict__ t_dm, const u16* __restrict__ gate, const u16* __restrict__ Wpo,
    const float* __restrict__ nw, const float* __restrict__ nb,
    float* __restrict__ out)
{
  __shared__ u16 t_s[128*128];   // [j][d] swizzled; becomes LN'd f16
  __shared__ u16 w_s[128*128];   // Wpo swizzled; reused as C staging after mfmas

  const int tid = threadIdx.x, lane = tid & 63, w = tid >> 6;
  const int col = lane & 15, hi = lane >> 4;
  const int bi = blockIdx.x >> 2;
  const int jc = (blockIdx.x & 3) * 128;

  // phase A: transpose-load t tile + load Wpo
  {
    int dd = tid >> 1, jh = (tid & 1) * 64;
    const u16* src = t_dm + (size_t)dd*262144 + (size_t)bi*512 + jc + jh;
    #pragma unroll
    for (int s=0;s<8;s++){
      uint4 v = *(const uint4*)(src + s*8);
      const u16* ev = (const u16*)&v;
      #pragma unroll
      for (int u=0;u<8;u++){
        int j = jh + s*8 + u;
        t_s[j*128 + SWZ8(j, dd)] = ev[u];
      }
    }
    const u16* wsrc = Wpo + (size_t)dd*128 + jh;
    #pragma unroll
    for (int s=0;s<8;s++){
      uint4 v = *(const uint4*)(wsrc + s*8);
      *(uint4*)(&w_s[dd*128 + SWZ8(dd, jh + s*8)]) = v;
    }
  }
  __syncthreads();

  // phase B: LayerNorm over d for each j (2 threads per j)
  {
    int j = tid >> 1, dh = (tid & 1) * 64;
    float s = 0.f, q = 0.f;
    #pragma unroll
    for (int sc=0;sc<8;sc++){
      uint4 v = *(const uint4*)(&t_s[j*128 + SWZ8(j, dh + sc*8)]);
      const u16* ev = (const u16*)&v;
      #pragma unroll
      for (int u=0;u<8;u++){ float f = h2f(ev[u]); s += f; q += f*f; }
    }
    s += __shfl_xor(s, 1); q += __shfl_xor(q, 1);
    float mu = s * 0.0078125f;
    float rs = rsqrtf(q*0.0078125f - mu*mu + 1e-5f);
    #pragma unroll
    for (int sc=0;sc<8;sc++){
      int db = dh + sc*8;
      u16* p = &t_s[j*128 + SWZ8(j, db)];
      uint4 v = *(uint4*)p;
      u16* ev = (u16*)&v;
      float4 w0 = *(const float4*)(nw + db);
      float4 w1 = *(const float4*)(nw + db + 4);
      float4 b0 = *(const float4*)(nb + db);
      float4 b1 = *(const float4*)(nb + db + 4);
      float wv[8] = {w0.x,w0.y,w0.z,w0.w,w1.x,w1.y,w1.z,w1.w};
      float bv[8] = {b0.x,b0.y,b0.z,b0.w,b1.x,b1.y,b1.z,b1.w};
      #pragma unroll
      for (int u=0;u<8;u++){
        float f = (h2f(ev[u]) - mu)*rs*wv[u] + bv[u];
        ev[u] = f2h(f);
      }
      *(uint4*)p = v;
    }
  }
  __syncthreads();

  // phase C: GEMM [128 j] x [128 d] @ [128 n][128 d]^T
  f32x4 acc[2][8];
  #pragma unroll
  for (int m=0;m<2;m++){
    #pragma unroll
    for (int n=0;n<8;n++) acc[m][n] = zero4();
  }
  #pragma unroll
  for (int kk=0;kk<4;kk++){
    f16x8 af[2];
    #pragma unroll
    for (int m=0;m<2;m++){
      int row = w*32 + m*16 + col;
      af[m] = *(const f16x8*)(&t_s[row*128 + SWZ8(row, kk*32 + hi*8)]);
    }
    #pragma unroll
    for (int n=0;n<8;n++){
      int rw = n*16 + col;
      f16x8 bv = *(const f16x8*)(&w_s[rw*128 + SWZ8(rw, kk*32 + hi*8)]);
      #pragma unroll
      for (int m=0;m<2;m++)
        acc[m][n] = __builtin_amdgcn_mfma_f32_16x16x32_f16(af[m], bv, acc[m][n], 0, 0, 0);
    }
  }
  __syncthreads();

  // phase D: stage C (f16) into w_s, then gated f32 write
  #pragma unroll
  for (int m=0;m<2;m++){
    #pragma unroll
    for (int n=0;n<8;n++){
      #pragma unroll
      for (int j=0;j<4;j++){
        int row = w*32 + m*16 + hi*4 + j, cl = n*16 + col;
        w_s[row*128 + SWZ8(row, cl)] = f2h(acc[m][n][j]);
      }
    }
  }
  __syncthreads();
  {
    int j = tid >> 1, dh = (tid & 1) * 64;
    size_t r = (size_t)bi*512 + jc + j;
    const u16* g = gate + r*128;
    float* o = out + r*128;
    #pragma unroll
    for (int sc=0;sc<8;sc++){
      int n8 = dh + sc*8;
      uint4 cv = *(const uint4*)(&w_s[j*128 + SWZ8(j, n8)]);
      uint4 gv = *(const uint4*)(g + n8);
      const u16* ce = (const u16*)&cv;
      const u16* ge = (const u16*)&gv;
      float4 o0, o1;
      o0.x = h2f(ce[0])*h2f(ge[0]);
      o0.y = h2f(ce[1])*h2f(ge[1]);
      o0.z = h2f(ce[2])*h2f(ge[2]);
      o0.w = h2f(ce[3])*h2f(ge[3]);
      o1.x = h2f(ce[4])*h2f(ge[4]);
      o1.y = h2f(ce[5])*h2f(ge[5]);
      o1.z = h2f(ce[6])*h2f(ge[6]);
      o1.w = h2f(ce[7])*h2f(ge[7]);
      *(float4*)(o + n8)     = o0;
      *(float4*)(o + n8 + 4) = o1;
    }
  }
}

extern "C" void kernel_launch(void* const* d_in, const int* in_sizes, int n_in,
                              void* d_out, int out_size, void* d_ws, size_t ws_size,
                              hipStream_t stream){
  const float* x    = (const float*)d_in[0];
  const float* mask = (const float*)d_in[1];
  const float* niw  = (const float*)d_in[2];
  const float* nib  = (const float*)d_in[3];
  const float* piw  = (const float*)d_in[4];
  const float* giw  = (const float*)d_in[5];
  const float* now  = (const float*)d_in[6];
  const float* nob  = (const float*)d_in[7];
  const float* pow_ = (const float*)d_in[8];
  const float* gow  = (const float*)d_in[9];
  float* out = (float*)d_out;

  // workspace layout (total ~256.2 MB)
  char* ws = (char*)d_ws;
  u16* a_t  = (u16*)(ws);                          // 64 MB  [128][262144]
  u16* b_t  = (u16*)(ws + (size_t)67108864);       // 64 MB
  u16* t_dm = (u16*)(ws + (size_t)134217728);      // 64 MB  [128][512][512]
  u16* gate = (u16*)(ws + (size_t)201326592);      // 64 MB  [262144][128]
  u16* W1   = (u16*)(ws + (size_t)268435456);      // 128 KB
  u16* Wgo  = W1 + 65536;                          // 32 KB
  u16* Wpo  = Wgo + 16384;                         // 32 KB

  k_prep<<<384, 256, 0, stream>>>(piw, giw, gow, pow_, W1, Wgo, Wpo);
  k_s1<<<2048, 256, 0, stream>>>(x, mask, niw, nib, W1, Wgo, a_t, b_t, gate);
  k_s2<<<dim3(16,128), 256, 0, stream>>>(a_t, b_t, t_dm);
  k_s3<<<2048, 256, 0, stream>>>(t_dm, gate, Wpo, now, nob, out);
}

// Round 4
// 307.799 us; speedup vs baseline: 1.3944x; 1.3944x over previous
//
#include <hip/hip_runtime.h>

typedef unsigned short u16;
typedef _Float16 f16x8 __attribute__((ext_vector_type(8)));
typedef float f32x4 __attribute__((ext_vector_type(4)));

__device__ __forceinline__ u16 f2h(float f){
  _Float16 h = (_Float16)f; u16 u; __builtin_memcpy(&u, &h, 2); return u;
}
__device__ __forceinline__ float h2f(u16 u){
  _Float16 h; __builtin_memcpy(&h, &u, 2); return (float)h;
}
__device__ __forceinline__ unsigned pk2h(float a, float b){
  auto r = __builtin_amdgcn_cvt_pkrtz(a, b);   // __fp16 ext_vector_type(2)
  unsigned u; __builtin_memcpy(&u, &r, 4); return u;
}
__device__ __forceinline__ float sigm(float x){ return 1.0f/(1.0f + __expf(-x)); }
__device__ __forceinline__ f32x4 zero4(){ f32x4 z; z[0]=0.f; z[1]=0.f; z[2]=0.f; z[3]=0.f; return z; }

#define SWZ8(row,k) ((k) ^ (((row)&7)<<3))

// ---------------- prep: pack weights to f16 ----------------
// W1[512][128]: MFMA-col cc of chunk c -> row c*64+cc.
//   n=cc>>4, col=cc&15, t=n>>1, typ=n&1, d = c*32 + t*16 + col
//   row holds (typ? g_in : p_in)[d][:]  -> p and g for dim d land in the SAME lane.
__global__ void k_prep(const float* __restrict__ p_in, const float* __restrict__ g_in,
                       const float* __restrict__ g_out, const float* __restrict__ p_out,
                       u16* __restrict__ W1, u16* __restrict__ Wgo, u16* __restrict__ Wpo){
  int t = blockIdx.x*256 + threadIdx.x;
  if (t < 65536){
    int row = t >> 7, k = t & 127;
    int c = row >> 6, cc = row & 63, n = cc >> 4, col = cc & 15;
    int d = c*32 + (n>>1)*16 + col;
    W1[t] = f2h((n&1) ? g_in[d*128+k] : p_in[d*128+k]);
  } else if (t < 81920){
    int u = t - 65536; Wgo[u] = f2h(g_out[u]);
  } else if (t < 98304){
    int u = t - 81920; Wpo[u] = f2h(p_out[u]);
  }
}

// ---------------- S1: LN + in-projections + gate ----------------
// block = 128 rows r = r0..r0+127.  a_t/b_t: [128 d][262144 r] f16. gate: [r][128 d] f16.
__global__ __launch_bounds__(256,3) void k_s1(
    const float* __restrict__ x, const float* __restrict__ mask,
    const float* __restrict__ nw, const float* __restrict__ nb,
    const u16* __restrict__ W1, const u16* __restrict__ Wgo,
    u16* __restrict__ a_t, u16* __restrict__ b_t, u16* __restrict__ gate)
{
  __shared__ u16 xh_s[128*128];   // 32KB: x_in f16 (phase 1); then h/gate staging
  __shared__ u16 w_s[64*128];     // 16KB: weight chunk, linear (source pre-swizzled)
  __shared__ float mask_s[128];

  const int tid = threadIdx.x, lane = tid & 63, w = tid >> 6;
  const int col = lane & 15, hi = lane >> 4;
  const int r0 = blockIdx.x * 128;

  // weight chunk prefetch via global_load_lds (16B/lane), source pre-swizzled (rule #21)
  auto issueW = [&](int c){
    const u16* wsrc = (c < 8) ? (W1 + c*8192) : (Wgo + (c-8)*8192);
    #pragma unroll
    for (int i = 0; i < 4; ++i){
      int idx8 = i*256 + tid;                 // 8-elem group id (0..1023)
      int nr = idx8 >> 4, kb = (idx8 & 15)*8;
      const u16* gp = wsrc + nr*128 + SWZ8(nr, kb);
      u16* lp = w_s + (size_t)(i*256 + w*64)*8;  // wave-uniform base (+lane*16B by HW)
      __builtin_amdgcn_global_load_lds((const __attribute__((address_space(1))) unsigned*)gp,
                                       (__attribute__((address_space(3))) unsigned*)lp, 16, 0, 0);
    }
  };

  if (tid < 128) mask_s[tid] = mask[r0 + tid];
  issueW(0);   // overlaps the whole LN phase

  // phase 1: LayerNorm — 4 rows/wave in parallel (16 lanes/row, 8 f32/lane)
  {
    const int g = lane >> 4, cl = lane & 15;
    float4 nwa = *(const float4*)(nw + cl*8);
    float4 nwb = *(const float4*)(nw + cl*8 + 4);
    float4 nba = *(const float4*)(nb + cl*8);
    float4 nbb = *(const float4*)(nb + cl*8 + 4);
    #pragma unroll
    for (int it = 0; it < 8; ++it){
      int row = w*32 + it*4 + g;
      const float* xr = x + (size_t)(r0+row)*128 + cl*8;
      float4 xa = *(const float4*)xr;
      float4 xb = *(const float4*)(xr + 4);
      float s = ((xa.x+xa.y)+(xa.z+xa.w)) + ((xb.x+xb.y)+(xb.z+xb.w));
      float q = xa.x*xa.x; q = fmaf(xa.y,xa.y,q); q = fmaf(xa.z,xa.z,q); q = fmaf(xa.w,xa.w,q);
      q = fmaf(xb.x,xb.x,q); q = fmaf(xb.y,xb.y,q); q = fmaf(xb.z,xb.z,q); q = fmaf(xb.w,xb.w,q);
      #pragma unroll
      for (int off = 1; off < 16; off <<= 1){ s += __shfl_xor(s, off); q += __shfl_xor(q, off); }
      float mu = s * 0.0078125f;
      float rs = rsqrtf(fmaxf(q*0.0078125f - mu*mu, 0.f) + 1e-5f);
      uint4 pv;
      pv.x = pk2h((xa.x-mu)*rs*nwa.x+nba.x, (xa.y-mu)*rs*nwa.y+nba.y);
      pv.y = pk2h((xa.z-mu)*rs*nwa.z+nba.z, (xa.w-mu)*rs*nwa.w+nba.w);
      pv.z = pk2h((xb.x-mu)*rs*nwb.x+nbb.x, (xb.y-mu)*rs*nwb.y+nbb.y);
      pv.w = pk2h((xb.z-mu)*rs*nwb.z+nbb.z, (xb.w-mu)*rs*nwb.w+nbb.w);
      *(uint4*)(&xh_s[row*128 + SWZ8(row, cl*8)]) = pv;
    }
  }
  __syncthreads();   // x_in visible; W(0) drained (compiler vmcnt(0) before barrier)

  // A-fragments register-cached once; xh_s is then dead -> reused as staging
  f16x8 af[2][4];
  #pragma unroll
  for (int m = 0; m < 2; ++m){
    #pragma unroll
    for (int kk = 0; kk < 4; ++kk){
      int row = w*32 + m*16 + col;
      af[m][kk] = *(const f16x8*)(&xh_s[row*128 + SWZ8(row, kk*32 + hi*8)]);
    }
  }
  // per-thread mask values (row = w*32 + m*16 + hi*4 + j)
  float mk[2][4];
  #pragma unroll
  for (int m = 0; m < 2; ++m)
    #pragma unroll
    for (int j = 0; j < 4; ++j) mk[m][j] = mask_s[w*32 + m*16 + hi*4 + j];

  for (int c = 0; c < 10; ++c){
    // B-fragments (16 x ds_read_b128, conflict-free via swizzle)
    f16x8 bf[4][4];
    #pragma unroll
    for (int n = 0; n < 4; ++n){
      #pragma unroll
      for (int kk = 0; kk < 4; ++kk){
        int nr = n*16 + col;
        bf[n][kk] = *(const f16x8*)(&w_s[nr*128 + SWZ8(nr, kk*32 + hi*8)]);
      }
    }
    __syncthreads();            // all waves done reading w_s (+ prev staging reads)
    if (c < 9) issueW(c+1);     // prefetch overlaps MFMA + epilogue below

    f32x4 acc[2][4];
    #pragma unroll
    for (int m = 0; m < 2; ++m)
      #pragma unroll
      for (int n = 0; n < 4; ++n) acc[m][n] = zero4();
    #pragma unroll
    for (int kk = 0; kk < 4; ++kk)
      #pragma unroll
      for (int m = 0; m < 2; ++m)
        #pragma unroll
        for (int n = 0; n < 4; ++n)
          acc[m][n] = __builtin_amdgcn_mfma_f32_16x16x32_f16(af[m][kk], bf[n][kk], acc[m][n], 0, 0, 0);

    if (c < 8){
      // h = p * sigmoid(g) * mask; p in acc[m][2t], g in acc[m][2t+1] (same lane!)
      u16* hbuf = xh_s + (c & 1)*4096;
      #pragma unroll
      for (int m = 0; m < 2; ++m){
        #pragma unroll
        for (int t2 = 0; t2 < 2; ++t2){
          f32x4 pv = acc[m][2*t2], gv = acc[m][2*t2+1];
          int dl = t2*16 + col;
          int rb = w*32 + m*16 + hi*4;
          int ad = dl*128 + (rb ^ ((dl & 15) << 3));
          float h0 = pv[0]*sigm(gv[0])*mk[m][0];
          float h1 = pv[1]*sigm(gv[1])*mk[m][1];
          float h2 = pv[2]*sigm(gv[2])*mk[m][2];
          float h3 = pv[3]*sigm(gv[3])*mk[m][3];
          uint2 uv; uv.x = pk2h(h0, h1); uv.y = pk2h(h2, h3);
          *(uint2*)(&hbuf[ad]) = uv;
        }
      }
      __syncthreads();          // staging visible; W(c+1) drained here
      {
        int dl = tid >> 3, seg = (tid & 7)*16;
        int dg = c*32 + dl;
        u16* dst = (dg < 128 ? a_t + (size_t)dg*262144 : b_t + (size_t)(dg-128)*262144) + r0;
        int sw = (dl & 15) << 3;
        uint4 v0 = *(const uint4*)(&hbuf[dl*128 + (seg ^ sw)]);
        uint4 v1 = *(const uint4*)(&hbuf[dl*128 + ((seg + 8) ^ sw)]);
        *(uint4*)(dst + seg)     = v0;
        *(uint4*)(dst + seg + 8) = v1;
      }
    } else {
      // gate chunk: gate = sigmoid(acc), row-major store
      #pragma unroll
      for (int m = 0; m < 2; ++m)
        #pragma unroll
        for (int n = 0; n < 4; ++n)
          #pragma unroll
          for (int j = 0; j < 4; ++j){
            int row = w*32 + m*16 + hi*4 + j;
            xh_s[row*68 + n*16 + col] = f2h(sigm(acc[m][n][j]));
          }
      __syncthreads();
      {
        int row = tid >> 1, base = (tid & 1)*32;
        u16* dst = gate + (size_t)(r0+row)*128 + (c-8)*64 + base;
        #pragma unroll
        for (int i2 = 0; i2 < 4; ++i2)
          *(uint4*)(dst + i2*8) = *(const uint4*)(&xh_s[row*68 + base + i2*8]);
      }
    }
  }
}

// ---------------- S2: 128 batched NT-GEMMs  t[d][i][j] = sum_k a[d][i][k] b[d][j][k] ----------------
__global__ __launch_bounds__(256) void k_s2(
    const u16* __restrict__ a_t, const u16* __restrict__ b_t, u16* __restrict__ t_dm)
{
  __shared__ u16 A_s[128*32];
  __shared__ u16 B_s[128*32];
  __shared__ u16 C_s[128*136];

  const int tid = threadIdx.x, lane = tid & 63, w = tid >> 6;
  const int col = lane & 15, hi = lane >> 4;
  const int d = blockIdx.y;
  const int ti = (blockIdx.x >> 2) * 128, tj = (blockIdx.x & 3) * 128;
  const u16* Ab = a_t + (size_t)d * 262144;
  const u16* Bb = b_t + (size_t)d * 262144;
  const int wr = (w >> 1) * 64, wc = (w & 1) * 64;

  f32x4 acc[4][4];
  #pragma unroll
  for (int m=0;m<4;m++){
    #pragma unroll
    for (int n=0;n<4;n++) acc[m][n] = zero4();
  }

  const int srow = lane >> 2;
  const int scol = (lane & 3) * 8;

  for (int k0 = 0; k0 < 512; k0 += 32){
    __syncthreads();
    #pragma unroll
    for (int j = 0; j < 2; ++j){
      int chunk = w*2 + j;
      int row = chunk*16 + srow;
      int e = scol ^ ((((row >> 1) & 3)) << 3);
      const unsigned int* gpA = (const unsigned int*)(Ab + (size_t)(ti + row)*512 + k0 + e);
      unsigned int* lpA = (unsigned int*)(&A_s[chunk*512]);
      __builtin_amdgcn_global_load_lds((const __attribute__((address_space(1))) unsigned int*)gpA,
                                       (__attribute__((address_space(3))) unsigned int*)lpA, 16, 0, 0);
      const unsigned int* gpB = (const unsigned int*)(Bb + (size_t)(tj + row)*512 + k0 + e);
      unsigned int* lpB = (unsigned int*)(&B_s[chunk*512]);
      __builtin_amdgcn_global_load_lds((const __attribute__((address_space(1))) unsigned int*)gpB,
                                       (__attribute__((address_space(3))) unsigned int*)lpB, 16, 0, 0);
    }
    __syncthreads();

    f16x8 af[4], bfv[4];
    #pragma unroll
    for (int m=0;m<4;m++){
      int row = wr + m*16 + col;
      af[m] = *(const f16x8*)(&A_s[row*32 + (hi*8 ^ ((((row>>1)&3))<<3))]);
    }
    #pragma unroll
    for (int n=0;n<4;n++){
      int row = wc + n*16 + col;
      bfv[n] = *(const f16x8*)(&B_s[row*32 + (hi*8 ^ ((((row>>1)&3))<<3))]);
    }
    #pragma unroll
    for (int m=0;m<4;m++){
      #pragma unroll
      for (int n=0;n<4;n++)
        acc[m][n] = __builtin_amdgcn_mfma_f32_16x16x32_f16(af[m], bfv[n], acc[m][n], 0, 0, 0);
    }
  }

  #pragma unroll
  for (int m=0;m<4;m++){
    #pragma unroll
    for (int n=0;n<4;n++){
      #pragma unroll
      for (int j=0;j<4;j++){
        int row = wr + m*16 + hi*4 + j, cl = wc + n*16 + col;
        C_s[row*136 + cl] = f2h(acc[m][n][j]);
      }
    }
  }
  __syncthreads();
  u16* dst0 = t_dm + (size_t)d*262144 + (size_t)ti*512 + tj;
  #pragma unroll
  for (int s=0;s<8;s++){
    int gi = s*256 + tid;
    int row = gi >> 4, seg = (gi & 15) * 8;
    *(uint4*)(dst0 + (size_t)row*512 + seg) = *(const uint4*)(&C_s[row*136 + seg]);
  }
}

// ---------------- S3: LN(t) @ p_out^T * gate -> out (f32) ----------------
__global__ __launch_bounds__(256) void k_s3(
    const u16* __restrict__ t_dm, const u16* __restrict__ gate, const u16* __restrict__ Wpo,
    const float* __restrict__ nw, const float* __restrict__ nb,
    float* __restrict__ out)
{
  __shared__ u16 t_s[128*128];
  __shared__ u16 w_s[128*128];

  const int tid = threadIdx.x, lane = tid & 63, w = tid >> 6;
  const int col = lane & 15, hi = lane >> 4;
  const int bi = blockIdx.x >> 2;
  const int jc = (blockIdx.x & 3) * 128;

  {
    int dd = tid >> 1, jh = (tid & 1) * 64;
    const u16* src = t_dm + (size_t)dd*262144 + (size_t)bi*512 + jc + jh;
    #pragma unroll
    for (int s=0;s<8;s++){
      uint4 v = *(const uint4*)(src + s*8);
      const u16* ev = (const u16*)&v;
      #pragma unroll
      for (int u=0;u<8;u++){
        int j = jh + s*8 + u;
        t_s[j*128 + SWZ8(j, dd)] = ev[u];
      }
    }
    const u16* wsrc = Wpo + (size_t)dd*128 + jh;
    #pragma unroll
    for (int s=0;s<8;s++){
      uint4 v = *(const uint4*)(wsrc + s*8);
      *(uint4*)(&w_s[dd*128 + SWZ8(dd, jh + s*8)]) = v;
    }
  }
  __syncthreads();

  {
    int j = tid >> 1, dh = (tid & 1) * 64;
    float s = 0.f, q = 0.f;
    #pragma unroll
    for (int sc=0;sc<8;sc++){
      uint4 v = *(const uint4*)(&t_s[j*128 + SWZ8(j, dh + sc*8)]);
      const u16* ev = (const u16*)&v;
      #pragma unroll
      for (int u=0;u<8;u++){ float f = h2f(ev[u]); s += f; q = fmaf(f,f,q); }
    }
    s += __shfl_xor(s, 1); q += __shfl_xor(q, 1);
    float mu = s * 0.0078125f;
    float rs = rsqrtf(fmaxf(q*0.0078125f - mu*mu, 0.f) + 1e-5f);
    #pragma unroll
    for (int sc=0;sc<8;sc++){
      int db = dh + sc*8;
      u16* p = &t_s[j*128 + SWZ8(j, db)];
      uint4 v = *(uint4*)p;
      u16* ev = (u16*)&v;
      float4 w0 = *(const float4*)(nw + db);
      float4 w1 = *(const float4*)(nw + db + 4);
      float4 b0 = *(const float4*)(nb + db);
      float4 b1 = *(const float4*)(nb + db + 4);
      float wv[8] = {w0.x,w0.y,w0.z,w0.w,w1.x,w1.y,w1.z,w1.w};
      float bv[8] = {b0.x,b0.y,b0.z,b0.w,b1.x,b1.y,b1.z,b1.w};
      #pragma unroll
      for (int u=0;u<8;u++){
        float f = (h2f(ev[u]) - mu)*rs*wv[u] + bv[u];
        ev[u] = f2h(f);
      }
      *(uint4*)p = v;
    }
  }
  __syncthreads();

  f32x4 acc[2][8];
  #pragma unroll
  for (int m=0;m<2;m++){
    #pragma unroll
    for (int n=0;n<8;n++) acc[m][n] = zero4();
  }
  #pragma unroll
  for (int kk=0;kk<4;kk++){
    f16x8 af[2];
    #pragma unroll
    for (int m=0;m<2;m++){
      int row = w*32 + m*16 + col;
      af[m] = *(const f16x8*)(&t_s[row*128 + SWZ8(row, kk*32 + hi*8)]);
    }
    #pragma unroll
    for (int n=0;n<8;n++){
      int rw = n*16 + col;
      f16x8 bv = *(const f16x8*)(&w_s[rw*128 + SWZ8(rw, kk*32 + hi*8)]);
      #pragma unroll
      for (int m=0;m<2;m++)
        acc[m][n] = __builtin_amdgcn_mfma_f32_16x16x32_f16(af[m], bv, acc[m][n], 0, 0, 0);
    }
  }
  __syncthreads();

  #pragma unroll
  for (int m=0;m<2;m++){
    #pragma unroll
    for (int n=0;n<8;n++){
      #pragma unroll
      for (int j=0;j<4;j++){
        int row = w*32 + m*16 + hi*4 + j, cl = n*16 + col;
        w_s[row*128 + SWZ8(row, cl)] = f2h(acc[m][n][j]);
      }
    }
  }
  __syncthreads();
  {
    int j = tid >> 1, dh = (tid & 1) * 64;
    size_t r = (size_t)bi*512 + jc + j;
    const u16* g = gate + r*128;
    float* o = out + r*128;
    #pragma unroll
    for (int sc=0;sc<8;sc++){
      int n8 = dh + sc*8;
      uint4 cv = *(const uint4*)(&w_s[j*128 + SWZ8(j, n8)]);
      uint4 gv = *(const uint4*)(g + n8);
      const u16* ce = (const u16*)&cv;
      const u16* ge = (const u16*)&gv;
      float4 o0, o1;
      o0.x = h2f(ce[0])*h2f(ge[0]);
      o0.y = h2f(ce[1])*h2f(ge[1]);
      o0.z = h2f(ce[2])*h2f(ge[2]);
      o0.w = h2f(ce[3])*h2f(ge[3]);
      o1.x = h2f(ce[4])*h2f(ge[4]);
      o1.y = h2f(ce[5])*h2f(ge[5]);
      o1.z = h2f(ce[6])*h2f(ge[6]);
      o1.w = h2f(ce[7])*h2f(ge[7]);
      *(float4*)(o + n8)     = o0;
      *(float4*)(o + n8 + 4) = o1;
    }
  }
}

extern "C" void kernel_launch(void* const* d_in, const int* in_sizes, int n_in,
                              void* d_out, int out_size, void* d_ws, size_t ws_size,
                              hipStream_t stream){
  const float* x    = (const float*)d_in[0];
  const float* mask = (const float*)d_in[1];
  const float* niw  = (const float*)d_in[2];
  const float* nib  = (const float*)d_in[3];
  const float* piw  = (const float*)d_in[4];
  const float* giw  = (const float*)d_in[5];
  const float* now  = (const float*)d_in[6];
  const float* nob  = (const float*)d_in[7];
  const float* pow_ = (const float*)d_in[8];
  const float* gow  = (const float*)d_in[9];
  float* out = (float*)d_out;

  char* ws = (char*)d_ws;
  u16* a_t  = (u16*)(ws);                          // 64 MB  [128][262144]
  u16* b_t  = (u16*)(ws + (size_t)67108864);       // 64 MB
  u16* t_dm = (u16*)(ws + (size_t)134217728);      // 64 MB  [128][512][512]
  u16* gate = (u16*)(ws + (size_t)201326592);      // 64 MB  [262144][128]
  u16* W1   = (u16*)(ws + (size_t)268435456);      // 128 KB
  u16* Wgo  = W1 + 65536;                          // 32 KB
  u16* Wpo  = Wgo + 16384;                         // 32 KB

  k_prep<<<384, 256, 0, stream>>>(piw, giw, gow, pow_, W1, Wgo, Wpo);
  k_s1<<<2048, 256, 0, stream>>>(x, mask, niw, nib, W1, Wgo, a_t, b_t, gate);
  k_s2<<<dim3(16,128), 256, 0, stream>>>(a_t, b_t, t_dm);
  k_s3<<<2048, 256, 0, stream>>>(t_dm, gate, Wpo, now, nob, out);
}